// Round 5
// baseline (418.756 us; speedup 1.0000x reference)
//
#include <hip/hip_runtime.h>
#include <hip/hip_bf16.h>
#include <cstdint>

#define BLOCK 512
#define BT 16            // batch rows per block (grid = 4096/16 = 256 = 1 block/CU)
#define RS_H 136         // h row stride in bf16 elems: 128 data (h0|h1) + 8 pad
#define RS_F 68          // hfin row stride (fp32)
#define XS   2052        // xlds row stride in shorts: 512*4 data + 4 pad

typedef __attribute__((ext_vector_type(8))) short bf16x8;
typedef __attribute__((ext_vector_type(4))) float f32x4;
typedef __attribute__((ext_vector_type(2))) float f32x2;
typedef __attribute__((ext_vector_type(2))) unsigned int u32x2;
typedef __attribute__((ext_vector_type(4))) unsigned int u32x4;

#define LOG2E 1.44269504f

static __device__ __forceinline__ float exp2_fast(float x) {
#if __has_builtin(__builtin_amdgcn_exp2f)
    return __builtin_amdgcn_exp2f(x);
#else
    return __expf(x * 0.69314718056f);
#endif
}
static __device__ __forceinline__ float rcp_fast(float x) {
    return __builtin_amdgcn_rcpf(x);
}
static __device__ __forceinline__ unsigned short f2bf(float f) {
    union { float f; unsigned u; } v; v.f = f;
    unsigned r = v.u + 0x7fffu + ((v.u >> 16) & 1u);   // RNE
    return (unsigned short)(r >> 16);
}
static __device__ __forceinline__ bf16x8 load_wfrag(const float* __restrict__ w, int off, float scale) {
    union { bf16x8 v; unsigned short s[8]; } u;
#pragma unroll
    for (int j = 0; j < 8; ++j) u.s[j] = f2bf(w[off + j] * scale);
    return u.v;
}

// One block = 16 batch rows. 8 waves: wv>>2 = layer (0/1), wv&3 = 16-col tile.
// Pipeline skew: at iteration `it`, L0-waves compute step it, L1-waves step it-1.
// Ping-pong h buffers => ONE barrier per iteration.
// Swapped MFMA operands (gates^T = W x state): lane holds 4 consecutive
// h-cols of one batch row => one ds_write_b64 per step.
// Gate weights pre-scaled by -log2e (i,f,o) / +2log2e (g): raw v_exp_f32 only.
// Merged-product activations: i*g and o*tanh(c) share one rcp each; forget
// rcp merged via R = rcp(d1*df).
// R5 (bit-identical math): persistent s_setprio(1) on L1 waves (role-diverse
// issue arbitration), x register double-buffer (prefetch next step's x under
// compute), packed f32x2 cell state, vectorized FC head.
extern "C" __global__ void __launch_bounds__(BLOCK, 2)
lstm_fused7(const float* __restrict__ x,
            const float* __restrict__ Wih0, const float* __restrict__ Whh0,
            const float* __restrict__ bih0, const float* __restrict__ bhh0,
            const float* __restrict__ Wih1, const float* __restrict__ Whh1,
            const float* __restrict__ bih1, const float* __restrict__ bhh1,
            const float* __restrict__ Wfc,  const float* __restrict__ bfc,
            float* __restrict__ out)
{
    __shared__ unsigned short hbuf[2][BT * RS_H]; // per row: [0:64)=h0, [64:128)=h1 (bf16)
    __shared__ float hfin[BT * RS_F];             // final h1 fp32 for the FC head
    __shared__ unsigned short xlds[BT * XS + 8];  // bf16 x, padded rows; last 8B = zero slot

    const int tid   = threadIdx.x;
    const int b0    = blockIdx.x * BT;
    const int lane  = tid & 63;
    const int wv    = tid >> 6;
    const int layer = wv >> 2;       // 0 or 1
    const int cb    = (wv & 3) * 16; // column base within this layer's 64 h-cols
    const int n16   = lane & 15;    // batch row (B-frag col / C col)
    const int quad  = lane >> 4;

    for (int i = tid; i < 2 * BT * RS_H; i += BLOCK)
        ((unsigned short*)hbuf)[i] = 0;

    // ---- stage x -> bf16 LDS (one time; RNE, bit-identical to on-the-fly).
    for (int i = tid; i < BT * 512; i += BLOCK) {
        const int r = i >> 9, t = i & 511;
        const f32x4 xv = *(const f32x4*)(x + ((size_t)(b0 + r) * 2048 + t * 4));
        const unsigned lo = (unsigned)f2bf(xv[0]) | ((unsigned)f2bf(xv[1]) << 16);
        const unsigned hi = (unsigned)f2bf(xv[2]) | ((unsigned)f2bf(xv[3]) << 16);
        *(u32x2*)&xlds[r * XS + t * 4] = (u32x2){lo, hi};
    }
    if (tid <= BT) {  // zero per-row pad (absorbs the t=512 prefetch) + broadcast zero slot
        const int off = (tid < BT) ? tid * XS + 2048 : BT * XS;
        *(u32x2*)&xlds[off] = (u32x2){0u, 0u};
    }

    // gate exponent scales: i,f,o -> -log2e ; g -> +2log2e
    const float gsc[4] = {-LOG2E, -LOG2E, 2.0f * LOG2E, -LOG2E};

    // ---- hoisted weight fragments (A-operand):
    // lane: gate-col gc = g*64+cb+n16, k = quad*8+j.
    // L0: s0,s1 = Whh0 (K=64), s2 = sparse Wih0 (x in k=0..3).
    // L1: s0,s1 = Wih1 (h0 path), s2,s3 = Whh1 (h1 path).
    bf16x8 wf[4][4];
    f32x4  biasv[4];   // C-operand: 4 distinct biases, rows quad*4+r
    if (layer == 0) {
#pragma unroll
        for (int g = 0; g < 4; ++g) {
            const int gc = g * 64 + cb + n16;
            const float s = gsc[g];
            wf[g][0] = load_wfrag(Whh0 + gc * 64, quad * 8, s);
            wf[g][1] = load_wfrag(Whh0 + gc * 64, 32 + quad * 8, s);
            union { bf16x8 v; unsigned short s_[8]; } u;
#pragma unroll
            for (int c = 0; c < 4; ++c)
                u.s_[c] = (quad == 0) ? f2bf(Wih0[gc * 4 + c] * s) : (unsigned short)0;
            u.s_[4] = 0; u.s_[5] = 0; u.s_[6] = 0; u.s_[7] = 0;
            wf[g][2] = u.v;
            const int gb = g * 64 + cb + quad * 4;
#pragma unroll
            for (int r = 0; r < 4; ++r)
                biasv[g][r] = (bih0[gb + r] + bhh0[gb + r]) * s;
        }
    } else {
#pragma unroll
        for (int g = 0; g < 4; ++g) {
            const int gc = g * 64 + cb + n16;
            const float s = gsc[g];
            wf[g][0] = load_wfrag(Wih1 + gc * 64, quad * 8, s);
            wf[g][1] = load_wfrag(Wih1 + gc * 64, 32 + quad * 8, s);
            wf[g][2] = load_wfrag(Whh1 + gc * 64, quad * 8, s);
            wf[g][3] = load_wfrag(Whh1 + gc * 64, 32 + quad * 8, s);
            const int gb = g * 64 + cb + quad * 4;
#pragma unroll
            for (int r = 0; r < 4; ++r)
                biasv[g][r] = (bih1[gb + r] + bhh1[gb + r]) * s;
        }
    }

    f32x2 cst2[2] = {{0.f, 0.f}, {0.f, 0.f}};   // cell state (PRE-SCALED by 2*log2e), packed

    // per-lane x read: quad0 lanes walk their batch row; quads 1-3 broadcast zero slot
    int xoff = (quad == 0) ? n16 * XS : BT * XS;     // shorts
    const int xadv = (quad == 0) ? 4 : 0;            // shorts per step

    // ---- hoisted per-lane LDS pointers (parity-static; all offsets become imms)
    const int rbase = n16 * RS_H + quad * 8;                    // state-frag base
    const int wbase = n16 * RS_H + layer * 64 + cb + quad * 4;  // 4 consecutive h-cols
    const unsigned short* __restrict__ rdp0 = &hbuf[1][rbase];  // read when it even
    const unsigned short* __restrict__ rdp1 = &hbuf[0][rbase];  // read when it odd
    unsigned short* __restrict__ wrp0 = &hbuf[0][wbase];        // write when it even
    unsigned short* __restrict__ wrp1 = &hbuf[1][wbase];        // write when it odd
    float* __restrict__ hfp = &hfin[n16 * RS_F + cb + quad * 4];

    const f32x2 onev  = {1.0f, 1.0f};
    const f32x2 k2l   = {2.0f * LOG2E, 2.0f * LOG2E};
    const f32x2 km2l  = {-2.0f * LOG2E, -2.0f * LOG2E};
    const f32x2 cclmp = {60.0f, 60.0f};   // c-overflow guard (c ~ 20.8; tanh==1 to 1e-18)

    __syncthreads();

    // x register double-buffer: xcur holds x(t) for the next L0 step
    u32x2 xcur = {0u, 0u};
    if (layer == 0) { xcur = *(const u32x2*)&xlds[xoff]; xoff += xadv; }
    else            __builtin_amdgcn_s_setprio(1);   // L1 = barrier-critical wave

    auto step = [&](const unsigned short* __restrict__ rp,
                    unsigned short* __restrict__ wp,
                    bool l0act, bool l1act, bool fin) __attribute__((always_inline)) {
        f32x4 acc[4];
        if (layer == 0) {
            if (l0act) {
                const bf16x8 s0 = *(const bf16x8*)(rp);          // h0 k=0..31 slice
                const bf16x8 s1 = *(const bf16x8*)(rp + 32);     // h0 k=32..63
                const u32x4 xt = {xcur.x, xcur.y, 0u, 0u};
                const bf16x8 sx = __builtin_bit_cast(bf16x8, xt);
                xcur = *(const u32x2*)&xlds[xoff];               // prefetch x(t+1)
                xoff += xadv;                                    // (t=512 hits zeroed pad)
#pragma unroll
                for (int g = 0; g < 4; ++g) {
                    acc[g] = __builtin_amdgcn_mfma_f32_16x16x32_bf16(wf[g][0], s0, biasv[g], 0, 0, 0);
                    acc[g] = __builtin_amdgcn_mfma_f32_16x16x32_bf16(wf[g][1], s1, acc[g], 0, 0, 0);
                    acc[g] = __builtin_amdgcn_mfma_f32_16x16x32_bf16(wf[g][2], sx, acc[g], 0, 0, 0);
                }
            }
        } else {
            if (l1act) {
                const bf16x8 s0 = *(const bf16x8*)(rp);          // h0 k=0..31
                const bf16x8 s1 = *(const bf16x8*)(rp + 32);     // h0 k=32..63
                const bf16x8 s2 = *(const bf16x8*)(rp + 64);     // h1 k=0..31
                const bf16x8 s3 = *(const bf16x8*)(rp + 96);     // h1 k=32..63
#pragma unroll
                for (int g = 0; g < 4; ++g) {
                    acc[g] = __builtin_amdgcn_mfma_f32_16x16x32_bf16(wf[g][0], s0, biasv[g], 0, 0, 0);
                    acc[g] = __builtin_amdgcn_mfma_f32_16x16x32_bf16(wf[g][1], s1, acc[g], 0, 0, 0);
                    acc[g] = __builtin_amdgcn_mfma_f32_16x16x32_bf16(wf[g][2], s2, acc[g], 0, 0, 0);
                    acc[g] = __builtin_amdgcn_mfma_f32_16x16x32_bf16(wf[g][3], s3, acc[g], 0, 0, 0);
                }
            }
        }
        const bool act = layer ? l1act : l0act;
        if (act) {
            // lane holds gates for batch row n16, h-cols cb+quad*4+{0..3}.
            // i*g = 2L(eg-1)/((1+ei)(eg+1)); f = 1/(1+ef); o*tanh(c) = (ec-1)/((1+eo)(ec+1))
            // merged rcp: R = 1/(d1*df) -> 1/d1 = R*df, 1/df = R*d1.
            unsigned hw0 = 0, hw1 = 0;
            float hf0 = 0.f, hf1 = 0.f, hf2 = 0.f, hf3 = 0.f;
#pragma unroll
            for (int p = 0; p < 2; ++p) {
                const f32x2 ei = {exp2_fast(acc[0][2*p]), exp2_fast(acc[0][2*p+1])};
                const f32x2 ef = {exp2_fast(acc[1][2*p]), exp2_fast(acc[1][2*p+1])};
                const f32x2 eg = {exp2_fast(acc[2][2*p]), exp2_fast(acc[2][2*p+1])};
                const f32x2 eo = {exp2_fast(acc[3][2*p]), exp2_fast(acc[3][2*p+1])};

                const f32x2 t2 = __builtin_elementwise_fma(eg, k2l, km2l); // 2L*(eg-1)
                const f32x2 d1 = (eg + onev) * (ei + onev);
                const f32x2 df = ef + onev;
                const f32x2 pr = d1 * df;
                const f32x2 R  = {rcp_fast(pr[0]), rcp_fast(pr[1])};
                const f32x2 P  = t2 * R * df;                              // 2L * i*g
                const f32x2 fv = R * d1;                                   // forget gate

                f32x2 c2 = __builtin_elementwise_fma(fv, cst2[p], P);      // 2L * c
                c2 = __builtin_elementwise_min(c2, cclmp);
                cst2[p] = c2;

                const f32x2 ec = {exp2_fast(c2[0]), exp2_fast(c2[1])};
                const f32x2 d2 = (ec + onev) * (eo + onev);
                const f32x2 r2 = {rcp_fast(d2[0]), rcp_fast(d2[1])};
                const f32x2 h  = (ec - onev) * r2;                         // o * tanh(c)

                union { __hip_bfloat162 b; unsigned u; } hb;
                hb.b = __float22bfloat162_rn(make_float2(h[0], h[1]));
                if (p == 0) { hw0 = hb.u; hf0 = h[0]; hf1 = h[1]; }
                else        { hw1 = hb.u; hf2 = h[0]; hf3 = h[1]; }
            }
            *(u32x2*)wp = (u32x2){hw0, hw1};       // ONE ds_write_b64 (4 h-cols)
            if (fin && layer == 1)
                *(f32x4*)hfp = (f32x4){hf0, hf1, hf2, hf3};
        }
        __syncthreads();   // the ONLY barrier per iteration (ping-pong makes it safe)
    };

    step(rdp0, wrp0, true,  false, false);          // it = 0   (L1 idle)
    for (int k = 0; k < 255; ++k) {                 // it = 1..510
        step(rdp1, wrp1, true, true, false);        //   odd
        step(rdp0, wrp0, true, true, false);        //   even
    }
    step(rdp1, wrp1, true,  true,  false);          // it = 511
    step(rdp0, wrp0, false, true,  true);           // it = 512 (L0 idle, hfin store)

    __builtin_amdgcn_s_setprio(0);

    // FC head: out[b0+m][k] = h1_final[m,:] . Wfc[k,:] + bfc[k]  (vectorized)
    if (tid < BT * 20) {
        const int m = tid / 20, k = tid % 20;
        const f32x4* __restrict__ hv = (const f32x4*)&hfin[m * RS_F];  // 272B stride: 16B-aligned
        const f32x4* __restrict__ wvv = (const f32x4*)&Wfc[k * 64];
        f32x4 a4 = {0.f, 0.f, 0.f, 0.f};
#pragma unroll
        for (int j = 0; j < 16; ++j)
            a4 = __builtin_elementwise_fma(hv[j], wvv[j], a4);
        out[(b0 + m) * 20 + k] = bfc[k] + ((a4[0] + a4[1]) + (a4[2] + a4[3]));
    }
}

extern "C" void kernel_launch(void* const* d_in, const int* in_sizes, int n_in,
                              void* d_out, int out_size, void* d_ws, size_t ws_size,
                              hipStream_t stream)
{
    (void)in_sizes; (void)n_in; (void)d_ws; (void)ws_size; (void)out_size;
    const float* xp    = (const float*)d_in[0];
    const float* Wih0p = (const float*)d_in[1];
    const float* Whh0p = (const float*)d_in[2];
    const float* bih0p = (const float*)d_in[3];
    const float* bhh0p = (const float*)d_in[4];
    const float* Wih1p = (const float*)d_in[5];
    const float* Whh1p = (const float*)d_in[6];
    const float* bih1p = (const float*)d_in[7];
    const float* bhh1p = (const float*)d_in[8];
    const float* Wfcp  = (const float*)d_in[9];
    const float* bfcp  = (const float*)d_in[10];

    lstm_fused7<<<dim3(256), dim3(BLOCK), 0, stream>>>(
        xp, Wih0p, Whh0p, bih0p, bhh0p, Wih1p, Whh1p, bih1p, bhh1p,
        Wfcp, bfcp, (float*)d_out);
}

// Round 8
// 416.112 us; speedup vs baseline: 1.0064x; 1.0064x over previous
//
#include <hip/hip_runtime.h>
#include <hip/hip_bf16.h>
#include <cstdint>

#define BLOCK 512
#define BT 16            // batch rows per block (grid = 4096/16 = 256 = 1 block/CU)
#define RS_H 136         // h row stride in bf16 elems: 128 data (h0|h1) + 8 pad
#define RS_F 68          // hfin row stride (fp32)
#define XS   2052        // xlds row stride in shorts: 512*4 data + 4 pad

typedef __attribute__((ext_vector_type(8))) short bf16x8;
typedef __attribute__((ext_vector_type(4))) float f32x4;
typedef __attribute__((ext_vector_type(2))) float f32x2;
typedef __attribute__((ext_vector_type(2))) unsigned int u32x2;
typedef __attribute__((ext_vector_type(4))) unsigned int u32x4;

#define LOG2E 1.44269504f

static __device__ __forceinline__ float exp2_fast(float x) {
#if __has_builtin(__builtin_amdgcn_exp2f)
    return __builtin_amdgcn_exp2f(x);
#else
    return __expf(x * 0.69314718056f);
#endif
}
static __device__ __forceinline__ float rcp_fast(float x) {
    return __builtin_amdgcn_rcpf(x);
}
static __device__ __forceinline__ unsigned short f2bf(float f) {
    union { float f; unsigned u; } v; v.f = f;
    unsigned r = v.u + 0x7fffu + ((v.u >> 16) & 1u);   // RNE
    return (unsigned short)(r >> 16);
}
static __device__ __forceinline__ bf16x8 load_wfrag(const float* __restrict__ w, int off, float scale) {
    union { bf16x8 v; unsigned short s[8]; } u;
#pragma unroll
    for (int j = 0; j < 8; ++j) u.s[j] = f2bf(w[off + j] * scale);
    return u.v;
}

// FINAL (revert to verified-best R4 kernel, bench 417.2 us / steady ~396 us).
// One block = 16 batch rows. 8 waves: wv>>2 = layer (0/1), wv&3 = 16-col tile.
// Pipeline skew: at iteration `it`, L0-waves compute step it, L1-waves step it-1.
// Ping-pong h buffers => ONE barrier per iteration.
// Swapped MFMA operands: gates^T = W x state, i.e. mfma(wf, state_frag).
// A/B lane maps are identical on 16x16x32 (idx = lane&15, k = quad*8+j), so all
// staged fragments are bit-identical to the unswapped version; only C flips:
// lane holds 4 CONSECUTIVE h-columns (rows = quad*4+reg = gate-col) of one
// batch row (col = lane&15) => the 4 h-stores merge into ONE ds_write_b64.
// Gate weights pre-scaled by -log2e (i,f,o) / +2log2e (g): raw v_exp_f32 only.
// Merged-product activations: i*g and o*tanh(c) share one rcp each; forget
// rcp merged via R = rcp(d1*df). x pre-converted to bf16 in LDS; bias as
// persistent MFMA C-operand; peeled it=0/511/512 + parity-unrolled hot loop
// with hoisted per-lane LDS pointers.
// Session note: spin-wait decoupled variants (R6/R7) deadlock-free by proof
// but killed the MI355X container twice each — barrier lockstep retained.
extern "C" __global__ void __launch_bounds__(BLOCK, 2)
lstm_fused6(const float* __restrict__ x,
            const float* __restrict__ Wih0, const float* __restrict__ Whh0,
            const float* __restrict__ bih0, const float* __restrict__ bhh0,
            const float* __restrict__ Wih1, const float* __restrict__ Whh1,
            const float* __restrict__ bih1, const float* __restrict__ bhh1,
            const float* __restrict__ Wfc,  const float* __restrict__ bfc,
            float* __restrict__ out)
{
    __shared__ unsigned short hbuf[2][BT * RS_H]; // per row: [0:64)=h0, [64:128)=h1 (bf16)
    __shared__ float hfin[BT * RS_F];             // final h1 fp32 for the FC head
    __shared__ unsigned short xlds[BT * XS + 8];  // bf16 x, padded rows; last 8B = zero slot

    const int tid   = threadIdx.x;
    const int b0    = blockIdx.x * BT;
    const int lane  = tid & 63;
    const int wv    = tid >> 6;
    const int layer = wv >> 2;       // 0 or 1
    const int cb    = (wv & 3) * 16; // column base within this layer's 64 h-cols
    const int n16   = lane & 15;    // batch row (B-frag col / C col)
    const int quad  = lane >> 4;

    for (int i = tid; i < 2 * BT * RS_H; i += BLOCK)
        ((unsigned short*)hbuf)[i] = 0;

    // ---- stage x -> bf16 LDS (one time; RNE, bit-identical to on-the-fly).
    for (int i = tid; i < BT * 512; i += BLOCK) {
        const int r = i >> 9, t = i & 511;
        const f32x4 xv = *(const f32x4*)(x + ((size_t)(b0 + r) * 2048 + t * 4));
        const unsigned lo = (unsigned)f2bf(xv[0]) | ((unsigned)f2bf(xv[1]) << 16);
        const unsigned hi = (unsigned)f2bf(xv[2]) | ((unsigned)f2bf(xv[3]) << 16);
        *(u32x2*)&xlds[r * XS + t * 4] = (u32x2){lo, hi};
    }
    if (tid <= BT) {  // zero per-row pad + the quads-1..3 broadcast zero slot
        const int off = (tid < BT) ? tid * XS + 2048 : BT * XS;
        *(u32x2*)&xlds[off] = (u32x2){0u, 0u};
    }

    // gate exponent scales: i,f,o -> -log2e ; g -> +2log2e
    const float gsc[4] = {-LOG2E, -LOG2E, 2.0f * LOG2E, -LOG2E};

    // ---- hoisted weight fragments (A-operand):
    // lane: gate-col gc = g*64+cb+n16, k = quad*8+j.
    // L0: s0,s1 = Whh0 (K=64), s2 = sparse Wih0 (x in k=0..3).
    // L1: s0,s1 = Wih1 (h0 path), s2,s3 = Whh1 (h1 path).
    bf16x8 wf[4][4];
    f32x4  biasv[4];   // C-operand: 4 distinct biases, rows quad*4+r
    if (layer == 0) {
#pragma unroll
        for (int g = 0; g < 4; ++g) {
            const int gc = g * 64 + cb + n16;
            const float s = gsc[g];
            wf[g][0] = load_wfrag(Whh0 + gc * 64, quad * 8, s);
            wf[g][1] = load_wfrag(Whh0 + gc * 64, 32 + quad * 8, s);
            union { bf16x8 v; unsigned short s_[8]; } u;
#pragma unroll
            for (int c = 0; c < 4; ++c)
                u.s_[c] = (quad == 0) ? f2bf(Wih0[gc * 4 + c] * s) : (unsigned short)0;
            u.s_[4] = 0; u.s_[5] = 0; u.s_[6] = 0; u.s_[7] = 0;
            wf[g][2] = u.v;
            const int gb = g * 64 + cb + quad * 4;
#pragma unroll
            for (int r = 0; r < 4; ++r)
                biasv[g][r] = (bih0[gb + r] + bhh0[gb + r]) * s;
        }
    } else {
#pragma unroll
        for (int g = 0; g < 4; ++g) {
            const int gc = g * 64 + cb + n16;
            const float s = gsc[g];
            wf[g][0] = load_wfrag(Wih1 + gc * 64, quad * 8, s);
            wf[g][1] = load_wfrag(Wih1 + gc * 64, 32 + quad * 8, s);
            wf[g][2] = load_wfrag(Whh1 + gc * 64, quad * 8, s);
            wf[g][3] = load_wfrag(Whh1 + gc * 64, 32 + quad * 8, s);
            const int gb = g * 64 + cb + quad * 4;
#pragma unroll
            for (int r = 0; r < 4; ++r)
                biasv[g][r] = (bih1[gb + r] + bhh1[gb + r]) * s;
        }
    }

    float cst[4] = {0.f, 0.f, 0.f, 0.f};   // cell state (PRE-SCALED by 2*log2e), h-cols quad*4+r

    // per-lane x read: quad0 lanes walk their batch row; quads 1-3 broadcast zero slot
    int xoff = (quad == 0) ? n16 * XS : BT * XS;     // shorts
    const int xadv = (quad == 0) ? 4 : 0;            // shorts per step

    // ---- hoisted per-lane LDS pointers (parity-static; all offsets become imms)
    const int rbase = n16 * RS_H + quad * 8;                    // state-frag base
    const int wbase = n16 * RS_H + layer * 64 + cb + quad * 4;  // 4 consecutive h-cols
    const unsigned short* __restrict__ rdp0 = &hbuf[1][rbase];  // read when it even
    const unsigned short* __restrict__ rdp1 = &hbuf[0][rbase];  // read when it odd
    unsigned short* __restrict__ wrp0 = &hbuf[0][wbase];        // write when it even
    unsigned short* __restrict__ wrp1 = &hbuf[1][wbase];        // write when it odd
    float* __restrict__ hfp = &hfin[n16 * RS_F + cb + quad * 4];

    const f32x2 onev  = {1.0f, 1.0f};
    const f32x2 k2l   = {2.0f * LOG2E, 2.0f * LOG2E};
    const f32x2 km2l  = {-2.0f * LOG2E, -2.0f * LOG2E};
    const f32x2 cclmp = {60.0f, 60.0f};   // c-overflow guard (c ~ 20.8; tanh==1 to 1e-18)

    __syncthreads();

    auto step = [&](const unsigned short* __restrict__ rp,
                    unsigned short* __restrict__ wp,
                    bool l0act, bool l1act, bool fin) __attribute__((always_inline)) {
        f32x4 acc[4];
        if (layer == 0) {
            if (l0act) {
                const bf16x8 s0 = *(const bf16x8*)(rp);          // h0 k=0..31 slice
                const bf16x8 s1 = *(const bf16x8*)(rp + 32);     // h0 k=32..63
                const u32x2 xr = *(const u32x2*)&xlds[xoff];     // quad0: x(t) bf16x4; else 0
                xoff += xadv;
                const u32x4 xt = {xr.x, xr.y, 0u, 0u};
                const bf16x8 sx = __builtin_bit_cast(bf16x8, xt);
#pragma unroll
                for (int g = 0; g < 4; ++g) {
                    acc[g] = __builtin_amdgcn_mfma_f32_16x16x32_bf16(wf[g][0], s0, biasv[g], 0, 0, 0);
                    acc[g] = __builtin_amdgcn_mfma_f32_16x16x32_bf16(wf[g][1], s1, acc[g], 0, 0, 0);
                    acc[g] = __builtin_amdgcn_mfma_f32_16x16x32_bf16(wf[g][2], sx, acc[g], 0, 0, 0);
                }
            }
        } else {
            if (l1act) {
                const bf16x8 s0 = *(const bf16x8*)(rp);          // h0 k=0..31
                const bf16x8 s1 = *(const bf16x8*)(rp + 32);     // h0 k=32..63
                const bf16x8 s2 = *(const bf16x8*)(rp + 64);     // h1 k=0..31
                const bf16x8 s3 = *(const bf16x8*)(rp + 96);     // h1 k=32..63
#pragma unroll
                for (int g = 0; g < 4; ++g) {
                    acc[g] = __builtin_amdgcn_mfma_f32_16x16x32_bf16(wf[g][0], s0, biasv[g], 0, 0, 0);
                    acc[g] = __builtin_amdgcn_mfma_f32_16x16x32_bf16(wf[g][1], s1, acc[g], 0, 0, 0);
                    acc[g] = __builtin_amdgcn_mfma_f32_16x16x32_bf16(wf[g][2], s2, acc[g], 0, 0, 0);
                    acc[g] = __builtin_amdgcn_mfma_f32_16x16x32_bf16(wf[g][3], s3, acc[g], 0, 0, 0);
                }
            }
        }
        const bool act = layer ? l1act : l0act;
        if (act) {
            // lane holds gates for batch row n16, h-cols cb+quad*4+{0..3}.
            // i*g = 2L(eg-1)/((1+ei)(eg+1)); f = 1/(1+ef); o*tanh(c) = (ec-1)/((1+eo)(ec+1))
            // merged rcp: R = 1/(d1*df) -> 1/d1 = R*df, 1/df = R*d1.
            unsigned hw0 = 0, hw1 = 0;
            float hf0 = 0.f, hf1 = 0.f, hf2 = 0.f, hf3 = 0.f;
#pragma unroll
            for (int p = 0; p < 2; ++p) {
                const f32x2 ei = {exp2_fast(acc[0][2*p]), exp2_fast(acc[0][2*p+1])};
                const f32x2 ef = {exp2_fast(acc[1][2*p]), exp2_fast(acc[1][2*p+1])};
                const f32x2 eg = {exp2_fast(acc[2][2*p]), exp2_fast(acc[2][2*p+1])};
                const f32x2 eo = {exp2_fast(acc[3][2*p]), exp2_fast(acc[3][2*p+1])};

                const f32x2 t2 = __builtin_elementwise_fma(eg, k2l, km2l); // 2L*(eg-1)
                const f32x2 d1 = (eg + onev) * (ei + onev);
                const f32x2 df = ef + onev;
                const f32x2 pr = d1 * df;
                const f32x2 R  = {rcp_fast(pr[0]), rcp_fast(pr[1])};
                const f32x2 P  = t2 * R * df;                              // 2L * i*g
                const f32x2 fv = R * d1;                                   // forget gate

                f32x2 cp = {cst[2*p], cst[2*p+1]};
                f32x2 c2 = __builtin_elementwise_fma(fv, cp, P);           // 2L * c
                c2 = __builtin_elementwise_min(c2, cclmp);
                cst[2*p] = c2[0]; cst[2*p+1] = c2[1];

                const f32x2 ec = {exp2_fast(c2[0]), exp2_fast(c2[1])};
                const f32x2 d2 = (ec + onev) * (eo + onev);
                const f32x2 r2 = {rcp_fast(d2[0]), rcp_fast(d2[1])};
                const f32x2 h  = (ec - onev) * r2;                         // o * tanh(c)

                union { __hip_bfloat162 b; unsigned u; } hb;
                hb.b = __float22bfloat162_rn(make_float2(h[0], h[1]));
                if (p == 0) { hw0 = hb.u; hf0 = h[0]; hf1 = h[1]; }
                else        { hw1 = hb.u; hf2 = h[0]; hf3 = h[1]; }
            }
            *(u32x2*)wp = (u32x2){hw0, hw1};       // ONE ds_write_b64 (4 h-cols)
            if (fin && layer == 1)
                *(f32x4*)hfp = (f32x4){hf0, hf1, hf2, hf3};
        }
        __syncthreads();   // the ONLY barrier per iteration (ping-pong makes it safe)
    };

    step(rdp0, wrp0, true,  false, false);          // it = 0   (L1 idle)
    for (int k = 0; k < 255; ++k) {                 // it = 1..510, zero conditionals
        step(rdp1, wrp1, true, true, false);        //   odd
        step(rdp0, wrp0, true, true, false);        //   even
    }
    step(rdp1, wrp1, true,  true,  false);          // it = 511
    step(rdp0, wrp0, false, true,  true);           // it = 512 (L0 idle, hfin store)

    // FC head: out[b0+m][k] = h1_final[m,:] . Wfc[k,:] + bfc[k]
    if (tid < BT * 20) {
        const int m = tid / 20, k = tid % 20;
        float acc = bfc[k];
#pragma unroll 8
        for (int j = 0; j < 64; ++j)
            acc += hfin[m * RS_F + j] * Wfc[k * 64 + j];
        out[(b0 + m) * 20 + k] = acc;
    }
}

extern "C" void kernel_launch(void* const* d_in, const int* in_sizes, int n_in,
                              void* d_out, int out_size, void* d_ws, size_t ws_size,
                              hipStream_t stream)
{
    (void)in_sizes; (void)n_in; (void)d_ws; (void)ws_size; (void)out_size;
    const float* xp    = (const float*)d_in[0];
    const float* Wih0p = (const float*)d_in[1];
    const float* Whh0p = (const float*)d_in[2];
    const float* bih0p = (const float*)d_in[3];
    const float* bhh0p = (const float*)d_in[4];
    const float* Wih1p = (const float*)d_in[5];
    const float* Whh1p = (const float*)d_in[6];
    const float* bih1p = (const float*)d_in[7];
    const float* bhh1p = (const float*)d_in[8];
    const float* Wfcp  = (const float*)d_in[9];
    const float* bfcp  = (const float*)d_in[10];

    lstm_fused6<<<dim3(256), dim3(BLOCK), 0, stream>>>(
        xp, Wih0p, Whh0p, bih0p, bhh0p, Wih1p, Whh1p, bih1p, bhh1p,
        Wfcp, bfcp, (float*)d_out);
}